// Round 8
// baseline (294.041 us; speedup 1.0000x reference)
//
#include <hip/hip_runtime.h>

// Problem constants (from reference)
#define NN   100000
#define EE   1600000
#define GG   500
#define NPGc 200
#define HH   64
#define NPERMc 3
#define C1   8192     // binning chunk (edges per block)
#define EB   196      // ceil(EE / C1)
#define XWB  256      // xw blocks (grid-stride over row chunks)
#define XWCH 782      // ceil(NN / 128) row chunks
#define HST  76       // H tile stride (f32): 16B-aligned b128 reads, uniform banks
#define BSTRIDE 4096  // fixed token-bucket stride per graph

// NOTES (hard-won):
// - 1024-thread blocks: VGPR force-capped at 64 on this toolchain -> spill. Never.
// - __launch_bounds__(512,2): observed cap 128 VGPR. (512,1) -> 256-reg ceiling;
//   LDS already pins 1 block/CU so nothing is lost.
// - conv is LDS-read-BW bound: B-frag redundancy (8 waves x all 4 ct-tiles)
//   ~= 448 KB/stage ~= 80% of block critical path. ct-pair x mt-group halves it.
// - r6 FAILURE: ct-pair waves write only their 2 ct-columns of pool ->
//   pool MUST be zero-initialized (dropped line caused absmax 4e-3).
// - r7: container infra failure; this source is the r6-fixed kernel, resubmitted.

typedef __fp16   h16x2 __attribute__((ext_vector_type(2)));   // pkrtz result type
typedef _Float16 f16x4 __attribute__((ext_vector_type(4)));
typedef _Float16 f16x8 __attribute__((ext_vector_type(8)));
typedef float    f32x4 __attribute__((ext_vector_type(4)));

// ---------------------------------------------------------------------------
// f32 -> f16 hi/lo fragment conversion (validated r4/r5)
// ---------------------------------------------------------------------------
__device__ __forceinline__ void cvt_hilo(f32x4 a, f32x4 b, f16x8& hi, f16x8& lo) {
    float f[8] = {a[0], a[1], a[2], a[3], b[0], b[1], b[2], b[3]};
#pragma unroll
    for (int j = 0; j < 8; j += 2) {
        h16x2 h = __builtin_amdgcn_cvt_pkrtz(f[j], f[j + 1]);
        h16x2 l = __builtin_amdgcn_cvt_pkrtz(f[j] - (float)h[0], f[j + 1] - (float)h[1]);
        hi[j] = (_Float16)h[0]; hi[j + 1] = (_Float16)h[1];
        lo[j] = (_Float16)l[0]; lo[j + 1] = (_Float16)l[1];
    }
}

__device__ __forceinline__ void cvt_hilo4(const float (&v)[4], f16x4& hv, f16x4& lv) {
#pragma unroll
    for (int i = 0; i < 4; i += 2) {
        h16x2 h = __builtin_amdgcn_cvt_pkrtz(v[i], v[i + 1]);
        h16x2 l = __builtin_amdgcn_cvt_pkrtz(v[i] - (float)h[0], v[i + 1] - (float)h[1]);
        hv[i] = (_Float16)h[0]; hv[i + 1] = (_Float16)h[1];
        lv[i] = (_Float16)l[0]; lv[i + 1] = (_Float16)l[1];
    }
}

__device__ __forceinline__ void cvt_hilo8(const float (&f)[8], f16x8& hi, f16x8& lo) {
#pragma unroll
    for (int j = 0; j < 8; j += 2) {
        h16x2 h = __builtin_amdgcn_cvt_pkrtz(f[j], f[j + 1]);
        h16x2 l = __builtin_amdgcn_cvt_pkrtz(f[j] - (float)h[0], f[j + 1] - (float)h[1]);
        hi[j] = (_Float16)h[0]; hi[j + 1] = (_Float16)h[1];
        lo[j] = (_Float16)l[0]; lo[j + 1] = (_Float16)l[1];
    }
}

// ---------------------------------------------------------------------------
// k_prep (merged): blocks [0,EB): bin edges into per-graph u16 token buckets.
// blocks [EB,EB+4): build W2/W3 hi/lo MFMA B-fragments into wf (c=32..63).
// blocks [EB+4,EB+4+XWB): xW = x @ W1[0:128], grid-strided over 782 row
// chunks with the per-block W1 frag table built ONCE (amortized 3x).
// ---------------------------------------------------------------------------
__global__ __launch_bounds__(512) void k_prep(const int* __restrict__ ei, int* __restrict__ gcnt,
                                              unsigned short* __restrict__ gtok,
                                              const float* __restrict__ w1, const float* __restrict__ w2,
                                              const float* __restrict__ w3, _Float16* __restrict__ wf,
                                              const float* __restrict__ x, float* __restrict__ xW) {
    __shared__ __align__(16) unsigned char smem[32 * 1024];
    int t = threadIdx.x;

    if (blockIdx.x >= EB + 4) {   // ---- xw part ----
        _Float16* wt = (_Float16*)smem;   // 32 KB: W1 hi/lo frags, c=0..31
#pragma unroll
        for (int it = 0; it < 4; ++it) {
            int tid = it * 512 + t;          // 0..2047
            int c = tid >> 6, lane2 = tid & 63;
            int q2 = lane2 >> 4, m2 = lane2 & 15;
            int kstep = c & 3, ct = (c >> 2) & 3, term = c >> 4;
            f16x8 v;
#pragma unroll
            for (int j = 0; j < 8; ++j) {
                float wv = w1[(kstep * 32 + q2 * 8 + j) * 64 + ct * 16 + m2];
                _Float16 hi = (_Float16)wv;
                float lo = wv - (float)hi;
                v[j] = term ? (_Float16)lo : hi;
            }
            *((f16x8*)(wt + c * 512) + lane2) = v;
        }
        __syncthreads();
        int lane = t & 63, w = t >> 6;
        int m = lane & 15, q = lane >> 4;
        for (int rb = blockIdx.x - (EB + 4); rb < XWCH; rb += XWB) {
            int rbase = rb * 128 + w * 16;
            int rowc = min(rbase + m, NN - 1);
            f16x8 Ah[4], Al[4];
#pragma unroll
            for (int ks = 0; ks < 4; ++ks) {
                const float* ar = x + (size_t)rowc * 128 + ks * 32 + q * 8;
                f32x4 f0 = *(const f32x4*)ar;
                f32x4 f1 = *(const f32x4*)(ar + 4);
                cvt_hilo(f0, f1, Ah[ks], Al[ks]);
            }
#pragma unroll
            for (int ct = 0; ct < 4; ++ct) {
                f32x4 acc = {0.f, 0.f, 0.f, 0.f};
#pragma unroll
                for (int ks = 0; ks < 4; ++ks) {
                    f16x8 Bh = *((const f16x8*)(wt + ((0 * 4 + ct) * 4 + ks) * 512) + lane);
                    f16x8 Bl = *((const f16x8*)(wt + ((1 * 4 + ct) * 4 + ks) * 512) + lane);
                    acc = __builtin_amdgcn_mfma_f32_16x16x32_f16(Ah[ks], Bh, acc, 0, 0, 0);
                    acc = __builtin_amdgcn_mfma_f32_16x16x32_f16(Al[ks], Bh, acc, 0, 0, 0);
                    acc = __builtin_amdgcn_mfma_f32_16x16x32_f16(Ah[ks], Bl, acc, 0, 0, 0);
                }
#pragma unroll
                for (int i = 0; i < 4; ++i) {
                    int r = rbase + q * 4 + i;
                    if (r < NN) xW[(size_t)r * 64 + ct * 16 + m] = acc[i];
                }
            }
        }
        return;
    }

    if (blockIdx.x >= EB) {   // ---- wprep part: W2/W3 only ----
        int tid = (blockIdx.x - EB) * 512 + t;   // 0..2047
        int c = 32 + (tid >> 6), lane = tid & 63;
        int q = lane >> 4, m = lane & 15;
        int c2 = c - 32;
        int kstep = c2 & 1, ct = (c2 >> 1) & 3, term = (c2 >> 3) & 1;
        const float* src = (c2 >> 4) ? w3 : w2;
        f16x8 v;
#pragma unroll
        for (int j = 0; j < 8; ++j) {
            float wv = src[(kstep * 32 + q * 8 + j) * 64 + ct * 16 + m];
            _Float16 hi = (_Float16)wv;
            float lo = wv - (float)hi;
            v[j] = term ? (_Float16)lo : hi;
        }
        *((f16x8*)(wf + c * 512) + lane) = v;
        return;
    }

    // ---- binning part ----
    unsigned short* stag = (unsigned short*)smem;          // 16 KB
    int* h   = (int*)(smem + 16384);                       // +2 KB
    int* esc = h + 512;
    int* cur = esc + 512;
    int* gb  = cur + 512;
    int base = blockIdx.x * C1;
    int nE = min(C1, EE - base);
    h[t] = 0; cur[t] = 0;
    __syncthreads();
    for (int i = t; i < nE; i += 512) atomicAdd(&h[ei[base + i] / NPGc], 1);
    __syncthreads();
    esc[t] = h[t];
    __syncthreads();
    for (int off = 1; off < 512; off <<= 1) {
        int u = (t >= off) ? esc[t - off] : 0;
        __syncthreads();
        esc[t] += u;
        __syncthreads();
    }
    esc[t] -= h[t];
    if (t < GG && h[t] > 0) gb[t] = atomicAdd(&gcnt[t], h[t]);
    __syncthreads();
    for (int i = t; i < nE; i += 512) {
        int s = ei[base + i], d = ei[EE + base + i];
        int g = s / NPGc;
        int ls = s - g * NPGc, ld = d - g * NPGc;
        int pos = esc[g] + atomicAdd(&cur[g], 1);
        stag[pos] = (unsigned short)(ls | (ld << 8));
    }
    __syncthreads();
    // parallel write-out: entry j's owner graph = max{g: esc[g] <= j}
    for (int j = t; j < nE; j += 512) {
        int g = 0;
#pragma unroll
        for (int step = 256; step > 0; step >>= 1) {
            int cand = g + step;
            if (cand < 512 && esc[cand] <= j) g = cand;
        }
        int off = gb[g] + (j - esc[g]);
        if (off < BSTRIDE) gtok[(size_t)g * BSTRIDE + off] = stag[j];
    }
}

// ---------------------------------------------------------------------------
// adjacency bytes (8) -> exact f16x8 A-fragment
// ---------------------------------------------------------------------------
__device__ __forceinline__ f16x8 cvt_a8(uint2 v) {
    f16x8 r;
#pragma unroll
    for (int k = 0; k < 4; ++k) r[k] = (_Float16)(float)((v.x >> (8 * k)) & 255u);
#pragma unroll
    for (int k = 0; k < 4; ++k) r[4 + k] = (_Float16)(float)((v.y >> (8 * k)) & 255u);
    return r;
}

// ---------------------------------------------------------------------------
// dense conv via MFMA, ct-pair x mt-group split (validated round 2):
// wave = (P = ct-pair, G = mt-group); G0 owns mts {0,1,2,3}, G1..3 own 3 mts.
// Each B-frag read feeds 3-4 MFMAs -> conv LDS reads halved vs mt-pair-only.
// First 2 mts' A-frags pre-converted f16 (Af); extras packed u8 (Ap),
// converted per-ks in the loop. Needs ~170 VGPR -> requires the 256 cap.
// ---------------------------------------------------------------------------
template <int NMT, bool POOL>
__device__ __forceinline__ void conv_ct(const _Float16* __restrict__ Tfh,
                                        const _Float16* __restrict__ Tfl,
                                        float* __restrict__ Hout,
                                        const f16x8 (&Af)[2][7], const uint2 (&Ap)[2][7],
                                        const int (&mts)[4], int ct0,
                                        int lane, int m, int q,
                                        const float (&dvc)[4][4], const float (&bias)[2],
                                        float (&poolv)[2]) {
    f32x4 acc[NMT][2];
#pragma unroll
    for (int j = 0; j < NMT; ++j)
#pragma unroll
        for (int c = 0; c < 2; ++c) acc[j][c] = (f32x4){0.f, 0.f, 0.f, 0.f};
#pragma unroll
    for (int ks = 0; ks < 7; ++ks) {
        f16x8 Bh[2], Bl[2];
#pragma unroll
        for (int c = 0; c < 2; ++c) {
            Bh[c] = *((const f16x8*)(Tfh + (ks * 4 + ct0 + c) * 512) + lane);
            Bl[c] = *((const f16x8*)(Tfl + (ks * 4 + ct0 + c) * 512) + lane);
        }
        f16x8 a2, a3;
        if (NMT > 2) a2 = cvt_a8(Ap[0][ks]);
        if (NMT > 3) a3 = cvt_a8(Ap[1][ks]);
#pragma unroll
        for (int c = 0; c < 2; ++c) {
            acc[0][c] = __builtin_amdgcn_mfma_f32_16x16x32_f16(Af[0][ks], Bh[c], acc[0][c], 0, 0, 0);
            acc[0][c] = __builtin_amdgcn_mfma_f32_16x16x32_f16(Af[0][ks], Bl[c], acc[0][c], 0, 0, 0);
            if (NMT > 1) {
                acc[1][c] = __builtin_amdgcn_mfma_f32_16x16x32_f16(Af[1][ks], Bh[c], acc[1][c], 0, 0, 0);
                acc[1][c] = __builtin_amdgcn_mfma_f32_16x16x32_f16(Af[1][ks], Bl[c], acc[1][c], 0, 0, 0);
            }
            if (NMT > 2) {
                acc[2][c] = __builtin_amdgcn_mfma_f32_16x16x32_f16(a2, Bh[c], acc[2][c], 0, 0, 0);
                acc[2][c] = __builtin_amdgcn_mfma_f32_16x16x32_f16(a2, Bl[c], acc[2][c], 0, 0, 0);
            }
            if (NMT > 3) {
                acc[3][c] = __builtin_amdgcn_mfma_f32_16x16x32_f16(a3, Bh[c], acc[3][c], 0, 0, 0);
                acc[3][c] = __builtin_amdgcn_mfma_f32_16x16x32_f16(a3, Bl[c], acc[3][c], 0, 0, 0);
            }
        }
    }
#pragma unroll
    for (int j = 0; j < NMT; ++j) {
        int rbase = mts[j] * 16 + q * 4;
#pragma unroll
        for (int c = 0; c < 2; ++c) {
            if (!POOL) {
#pragma unroll
                for (int i = 0; i < 4; ++i)
                    Hout[(rbase + i) * HST + (ct0 + c) * 16 + m] =
                        fmaxf(fmaf(dvc[j][i], acc[j][c][i], bias[c]), 0.f);
            } else {
                float pl = 0.f;
#pragma unroll
                for (int i = 0; i < 4; ++i) {
                    float o = fmaxf(fmaf(dvc[j][i], acc[j][c][i], bias[c]), 0.f);
                    if (rbase + i < NPGc) pl += o;
                }
                poolv[c] += pl;
            }
        }
    }
}

// ---------------------------------------------------------------------------
// dense GEMM (mt-pair x all 4 ct, W-fragments hoisted out of mi loop).
// T written directly as hi/lo B-frags (validated layout).
// ---------------------------------------------------------------------------
__device__ __forceinline__ void gemm_mfma(const float* __restrict__ H,
                                          _Float16* __restrict__ Tfh, _Float16* __restrict__ Tfl,
                                          const _Float16* __restrict__ wf, int w, int lane,
                                          int m, int q, int nmt, const float (&dvg)[2][4]) {
    f16x8 Ah[2][2], Al[2][2];
#pragma unroll
    for (int mi = 0; mi < 2; ++mi) {
        if (mi >= nmt) break;
        int mt = w + 8 * mi;
#pragma unroll
        for (int ks = 0; ks < 2; ++ks) {
            const float* ap = H + (mt * 16 + m) * HST + ks * 32 + 8 * q;
            f32x4 a = *(const f32x4*)ap;
            f32x4 b = *(const f32x4*)(ap + 4);
            cvt_hilo(a, b, Ah[mi][ks], Al[mi][ks]);
        }
    }
#pragma unroll
    for (int ct = 0; ct < 4; ++ct) {
        f16x8 Bh0 = *((const f16x8*)(wf + ((0 * 4 + ct) * 2 + 0) * 512) + lane);
        f16x8 Bh1 = *((const f16x8*)(wf + ((0 * 4 + ct) * 2 + 1) * 512) + lane);
        f16x8 Bl0 = *((const f16x8*)(wf + ((1 * 4 + ct) * 2 + 0) * 512) + lane);
        f16x8 Bl1 = *((const f16x8*)(wf + ((1 * 4 + ct) * 2 + 1) * 512) + lane);
#pragma unroll
        for (int mi = 0; mi < 2; ++mi) {
            if (mi >= nmt) break;
            int mt = w + 8 * mi;
            f32x4 acc = {0.f, 0.f, 0.f, 0.f};
            acc = __builtin_amdgcn_mfma_f32_16x16x32_f16(Ah[mi][0], Bh0, acc, 0, 0, 0);
            acc = __builtin_amdgcn_mfma_f32_16x16x32_f16(Al[mi][0], Bh0, acc, 0, 0, 0);
            acc = __builtin_amdgcn_mfma_f32_16x16x32_f16(Ah[mi][0], Bl0, acc, 0, 0, 0);
            acc = __builtin_amdgcn_mfma_f32_16x16x32_f16(Ah[mi][1], Bh1, acc, 0, 0, 0);
            acc = __builtin_amdgcn_mfma_f32_16x16x32_f16(Al[mi][1], Bh1, acc, 0, 0, 0);
            acc = __builtin_amdgcn_mfma_f32_16x16x32_f16(Ah[mi][1], Bl1, acc, 0, 0, 0);
            float o[4];
#pragma unroll
            for (int i = 0; i < 4; ++i) o[i] = acc[i] * dvg[mi][i];
            f16x4 hv, lv;
            cvt_hilo4(o, hv, lv);
            int quad = ((mt & 1) << 1) + (q >> 1);
            int j0 = (q & 1) << 2;
            int lanep = m + (quad << 4);
            int off = ((mt >> 1) * 4 + ct) * 512 + lanep * 8 + j0;
            *(f16x4*)(Tfh + off) = hv;
            *(f16x4*)(Tfl + off) = lv;
        }
    }
}

// ---------------------------------------------------------------------------
// Fused kernel: one block (512 thr, 8 waves) per graph. Conv uses
// (ct-pair x mt-group) roles (halved LDS reads); gemm uses mt-pair roles.
// __launch_bounds__(512, 1): 8 waves/CU -> 256-VGPR ceiling (LDS already
// pins 1 block/CU). ~156 KB LDS.
// ---------------------------------------------------------------------------
__global__ __launch_bounds__(512, 1) void k_fused(
    const float* __restrict__ xW, const float* __restrict__ perm,
    const float* __restrict__ w1tail,
    const float* __restrict__ b1, const float* __restrict__ b2, const float* __restrict__ b3,
    const _Float16* __restrict__ wsW23,
    const int* __restrict__ gcnt, const unsigned short* __restrict__ gtok,
    const float* __restrict__ a1w, const float* __restrict__ a1b,
    const float* __restrict__ a2w, const float* __restrict__ a2b,
    float* __restrict__ out) {
    __shared__ __align__(16) float Hm[15808];            // union: A8 build (46592B) / H f32 (stride 76)
    __shared__ __align__(16) _Float16 Tfh[28 * 512];     // T hi frags  (28 KB)
    __shared__ __align__(16) _Float16 Tfl[28 * 512];     // T lo frags  (28 KB)
    __shared__ __align__(16) _Float16 wlds[16384];       // W2 frags [0..8K), W3 [8K..16K)
    __shared__ float w1r[640];
    __shared__ float dv[224];
    __shared__ float pool[8 * 64];
    __shared__ unsigned char idsl[672];

    unsigned char* A8  = (unsigned char*)Hm;
    unsigned int*  A32 = (unsigned int*)Hm;

    int g = blockIdx.x, t = threadIdx.x;
    int lane = t & 63, w = t >> 6;          // w 0..7
    int m = lane & 15, q = lane >> 4;
    int P = w & 1, G = w >> 1;              // ct-pair, mt-group
    int ct0 = P * 2;
    int nbase = g * NPGc;
    int cnt = min(gcnt[g], BSTRIDE);
    const unsigned short* tok = gtok + (size_t)g * BSTRIDE;

    // stage W2/W3 frags + w1 tail rows; zero adjacency; zero dv pad rows;
    // zero pool (REQUIRED: ct-pair waves write only their 2 ct-columns)
    for (int i = t; i < 2048; i += 512) ((f16x8*)wlds)[i] = ((const f16x8*)wsW23)[i];
    for (int i = t; i < 640; i += 512) w1r[i] = w1tail[i];
    for (int i = t; i < 2912; i += 512) ((uint4*)A8)[i] = make_uint4(0, 0, 0, 0);
    if (t < 16) dv[208 + t] = 0.f;
    pool[t] = 0.f;
    __syncthreads();
    // build adjacency (u8 packed atomics) + self-loops
    for (int i = t; i < cnt; i += 512) {
        int tk = tok[i];
        int addr = (tk >> 8) * 224 + (tk & 255);
        atomicAdd(&A32[addr >> 2], 1u << ((addr & 3) * 8));
    }
    if (t < NPGc) { int a = t * 225; atomicAdd(&A32[a >> 2], 1u << ((a & 3) * 8)); }
    // one-hot ids for the 3 perms
    for (int i = t; i < 672; i += 512) {
        int p = i / 224, nd = i - p * 224;
        int id = 0;
        if (nd < NPGc) {
            const float* pp = perm + ((size_t)p * NN + nbase + nd) * 10;
            float best = pp[0];
#pragma unroll
            for (int k = 1; k < 10; ++k) { float v = pp[k]; if (v > best) { best = v; id = k; } }
        }
        idsl[i] = (unsigned char)id;
    }
    __syncthreads();
    // A-fragments for this wave's mt-group: first 2 mts as f16 frags (Af),
    // extra mts packed u8 (Ap). deg = in-register byte row sum + shfl -> dv.
    int nmtc = (G == 0) ? 4 : 3;
    int mts[4];
#pragma unroll
    for (int j = 0; j < 4; ++j) mts[j] = (G == 0) ? j : (1 + 3 * G + j);
    if (G != 0) mts[3] = 0;   // unused slot
    f16x8 Af[2][7];
    uint2  Ap[2][7];
#pragma unroll
    for (int j = 0; j < 4; ++j) {
        if (j < nmtc) {
            int mt = mts[j];
            unsigned su = 0;
#pragma unroll
            for (int ks = 0; ks < 7; ++ks) {
                uint2 v = *(const uint2*)(A8 + (mt * 16 + m) * 224 + ks * 32 + q * 8);
                su += (v.x & 255u) + ((v.x >> 8) & 255u) + ((v.x >> 16) & 255u) + (v.x >> 24);
                su += (v.y & 255u) + ((v.y >> 8) & 255u) + ((v.y >> 16) & 255u) + (v.y >> 24);
                if (j < 2) Af[j][ks] = cvt_a8(v);
                else       Ap[j - 2][ks] = v;
            }
            float rs = (float)su;
            rs += __shfl_xor(rs, 16);
            rs += __shfl_xor(rs, 32);
            if (P == 0 && q == 0) dv[mt * 16 + m] = (rs > 0.f) ? rsqrtf(rs) : 0.f;
        }
    }
    __syncthreads();   // A8 region now dead -> H takes over; dv ready

    float dvc[4][4];
#pragma unroll
    for (int j = 0; j < 4; ++j)
#pragma unroll
        for (int i = 0; i < 4; ++i)
            dvc[j][i] = (j < nmtc) ? dv[mts[j] * 16 + q * 4 + i] : 0.f;
    float dvg[2][4];
#pragma unroll
    for (int mi = 0; mi < 2; ++mi) {
        int mt = w + 8 * mi;
#pragma unroll
        for (int i = 0; i < 4; ++i)
            dvg[mi][i] = (mt < 13) ? dv[mt * 16 + q * 4 + i] : 0.f;
    }
    int nmtg = (w < 5) ? 2 : 1;
    float bb1[2], bb2[2], bb3[2];
#pragma unroll
    for (int c = 0; c < 2; ++c) {
        bb1[c] = b1[(ct0 + c) * 16 + m];
        bb2[c] = b2[(ct0 + c) * 16 + m];
        bb3[c] = b3[(ct0 + c) * 16 + m];
    }
    float poolv[2] = {0.f, 0.f};

    for (int p = 0; p < NPERMc; ++p) {
        // conv1 input -> T frags: val = dv*(xW + w1row[id]); 8-node chunks
        // {w, w+8, w+16, w+24}; single b128 store (uniform bank footprint)
        const unsigned char* ids = idsl + p * 224;
#pragma unroll
        for (int k = 0; k < 4; ++k) {
            int c8 = w + 8 * k;
            if (c8 < 28) {
                int nd0 = c8 * 8;
                float vals[8];
#pragma unroll
                for (int i = 0; i < 8; ++i) {
                    int nd = nd0 + i;
                    float xv = (nd < NPGc) ? xW[(size_t)(nbase + nd) * 64 + lane] : 0.f;
                    vals[i] = dv[nd] * (xv + w1r[ids[nd] * 64 + lane]);  // dv=0 kills pad rows
                }
                f16x8 hv, lv;
                cvt_hilo8(vals, hv, lv);
                int off = ((c8 >> 2) * 4 + q) * 512 + (m + ((c8 & 3) << 4)) * 8;
                *(f16x8*)(Tfh + off) = hv;
                *(f16x8*)(Tfl + off) = lv;
            }
        }
        __syncthreads();
        if (G == 0) conv_ct<4, false>(Tfh, Tfl, Hm, Af, Ap, mts, ct0, lane, m, q, dvc, bb1, poolv);
        else        conv_ct<3, false>(Tfh, Tfl, Hm, Af, Ap, mts, ct0, lane, m, q, dvc, bb1, poolv);
        __syncthreads();
        gemm_mfma(Hm, Tfh, Tfl, wlds, w, lane, m, q, nmtg, dvg);             // dv*(h1@W2) -> T
        __syncthreads();
        if (G == 0) conv_ct<4, false>(Tfh, Tfl, Hm, Af, Ap, mts, ct0, lane, m, q, dvc, bb2, poolv);
        else        conv_ct<3, false>(Tfh, Tfl, Hm, Af, Ap, mts, ct0, lane, m, q, dvc, bb2, poolv);
        __syncthreads();
        gemm_mfma(Hm, Tfh, Tfl, wlds + 8192, w, lane, m, q, nmtg, dvg);      // dv*(h2@W3) -> T
        __syncthreads();
        if (G == 0) conv_ct<4, true>(Tfh, Tfl, Hm, Af, Ap, mts, ct0, lane, m, q, dvc, bb3, poolv);
        else        conv_ct<3, true>(Tfh, Tfl, Hm, Af, Ap, mts, ct0, lane, m, q, dvc, bb3, poolv);
        __syncthreads();
    }

    // reduce pool: over q-groups (shfl) then over waves (LDS), then head MLP
#pragma unroll
    for (int c = 0; c < 2; ++c) {
        float v = poolv[c];
        v += __shfl_xor(v, 16);
        v += __shfl_xor(v, 32);
        if (q == 0) pool[w * 64 + (ct0 + c) * 16 + m] = v;
    }
    __syncthreads();
    if (t < 64) {
        float tot = 0.f;
#pragma unroll
        for (int i = 0; i < 8; ++i) tot += pool[i * 64 + t];
        pool[t] = tot * (1.0f / (NPGc * NPERMc));   // gsum
    }
    __syncthreads();
    if (t < 16) {
        float a = a1b[t];
        for (int k = 0; k < 64; ++k) a = fmaf(pool[k], a1w[k * 16 + t], a);
        pool[64 + t] = fmaxf(a, 0.f);
    }
    __syncthreads();
    if (t == 0) {
        float o = a2b[0];
#pragma unroll
        for (int i = 0; i < 16; ++i) o = fmaf(pool[64 + i], a2w[i], o);
        out[g] = o;
    }
}

// ---------------------------------------------------------------------------

static inline size_t alignup(size_t x) { return (x + 255) & ~(size_t)255; }

extern "C" void kernel_launch(void* const* d_in, const int* in_sizes, int n_in,
                              void* d_out, int out_size, void* d_ws, size_t ws_size,
                              hipStream_t stream) {
    const float* x    = (const float*)d_in[0];
    const int*   ei   = (const int*)d_in[1];
    // d_in[2] = batch_ids (unused: graphs are exactly 200 nodes each)
    const float* perm = (const float*)d_in[3];
    const float* w1   = (const float*)d_in[4];
    const float* b1   = (const float*)d_in[5];
    const float* w2   = (const float*)d_in[6];
    const float* b2   = (const float*)d_in[7];
    const float* w3   = (const float*)d_in[8];
    const float* b3   = (const float*)d_in[9];
    const float* a1w  = (const float*)d_in[10];
    const float* a1b  = (const float*)d_in[11];
    const float* a2w  = (const float*)d_in[12];
    const float* a2b  = (const float*)d_in[13];
    float* out = (float*)d_out;

    char* p = (char*)d_ws;
    auto take = [&](size_t bytes) { char* r = p; p += alignup(bytes); return r; };
    float*          xW   = (float*)take((size_t)NN * 64 * 4);
    unsigned short* gtok = (unsigned short*)take((size_t)GG * BSTRIDE * 2);
    _Float16*       wsW  = (_Float16*)take((size_t)64 * 512 * 2);
    int*            gcnt = (int*)take(512 * 4);
    (void)hipMemsetAsync(gcnt, 0, 512 * 4, stream);

    k_prep<<<EB + 4 + XWB, 512, 0, stream>>>(ei, gcnt, gtok, w1, w2, w3, wsW, x, xW);
    k_fused<<<GG, 512, 0, stream>>>(xW, perm, w1 + 128 * 64, b1, b2, b3,
                                    wsW + 32 * 512, gcnt, gtok,
                                    a1w, a1b, a2w, a2b, out);
}

// Round 9
// 231.115 us; speedup vs baseline: 1.2723x; 1.2723x over previous
//
#include <hip/hip_runtime.h>

// Problem constants (from reference)
#define NN   100000
#define EE   1600000
#define GG   500
#define NPGc 200
#define HH   64
#define NPERMc 3
#define C1   8192     // binning chunk (edges per block)
#define EB   196      // ceil(EE / C1)
#define XWB  256      // xw blocks (grid-stride over row chunks)
#define XWCH 782      // ceil(NN / 128) row chunks
#define HST  76       // H tile stride (f32): 16B-aligned b128 reads, uniform banks
#define BSTRIDE 4096  // fixed token-bucket stride per graph

// NOTES (hard-won, 8 rounds):
// - 1024-thread blocks: VGPR force-capped at 64 -> spill. Never.
// - 512-thread blocks: VGPR hard-clamped at 128 on this toolchain REGARDLESS
//   of __launch_bounds__ 2nd arg ((512,1) and (512,2) both clamp; (512,1)
//   spilled at 128 rather than allocating more). Any conv partition needing
//   >128 live VGPRs (ct-split, mt-group, 32x32 tiles) is permanently dead.
// - conv is LDS-read-bound (~52% of block cycles at the 85 B/cyc b128
//   ceiling, conflict-free); fixes all need >128 VGPR or +56KB LDS. Wall.
// - r6: ct-split pool must be zero-init'd (stale-LDS absmax 4e-3).
// - This source = r5 best (229.6 us total, k_fused 94-96 us, VGPR 124,
//   no spill) + LDS-staged W1 table in k_prep's xw role.

typedef __fp16   h16x2 __attribute__((ext_vector_type(2)));   // pkrtz result type
typedef _Float16 f16x4 __attribute__((ext_vector_type(4)));
typedef _Float16 f16x8 __attribute__((ext_vector_type(8)));
typedef float    f32x4 __attribute__((ext_vector_type(4)));

// ---------------------------------------------------------------------------
// f32 -> f16 hi/lo fragment conversion (validated r4/r5)
// ---------------------------------------------------------------------------
__device__ __forceinline__ void cvt_hilo(f32x4 a, f32x4 b, f16x8& hi, f16x8& lo) {
    float f[8] = {a[0], a[1], a[2], a[3], b[0], b[1], b[2], b[3]};
#pragma unroll
    for (int j = 0; j < 8; j += 2) {
        h16x2 h = __builtin_amdgcn_cvt_pkrtz(f[j], f[j + 1]);
        h16x2 l = __builtin_amdgcn_cvt_pkrtz(f[j] - (float)h[0], f[j + 1] - (float)h[1]);
        hi[j] = (_Float16)h[0]; hi[j + 1] = (_Float16)h[1];
        lo[j] = (_Float16)l[0]; lo[j + 1] = (_Float16)l[1];
    }
}

__device__ __forceinline__ void cvt_hilo4(const float (&v)[4], f16x4& hv, f16x4& lv) {
#pragma unroll
    for (int i = 0; i < 4; i += 2) {
        h16x2 h = __builtin_amdgcn_cvt_pkrtz(v[i], v[i + 1]);
        h16x2 l = __builtin_amdgcn_cvt_pkrtz(v[i] - (float)h[0], v[i + 1] - (float)h[1]);
        hv[i] = (_Float16)h[0]; hv[i + 1] = (_Float16)h[1];
        lv[i] = (_Float16)l[0]; lv[i + 1] = (_Float16)l[1];
    }
}

__device__ __forceinline__ void cvt_hilo8(const float (&f)[8], f16x8& hi, f16x8& lo) {
#pragma unroll
    for (int j = 0; j < 8; j += 2) {
        h16x2 h = __builtin_amdgcn_cvt_pkrtz(f[j], f[j + 1]);
        h16x2 l = __builtin_amdgcn_cvt_pkrtz(f[j] - (float)h[0], f[j + 1] - (float)h[1]);
        hi[j] = (_Float16)h[0]; hi[j + 1] = (_Float16)h[1];
        lo[j] = (_Float16)l[0]; lo[j + 1] = (_Float16)l[1];
    }
}

// ---------------------------------------------------------------------------
// k_prep (merged): blocks [0,EB): bin edges into per-graph u16 token buckets.
// blocks [EB,EB+4): build W2/W3 hi/lo MFMA B-fragments into wf (c=32..63).
// blocks [EB+4,EB+4+XWB): xW = x @ W1[0:128], grid-strided over 782 row
// chunks. W1 rows are first staged into LDS with coalesced float4 loads,
// then the frag table is built from LDS (replaces ~16K scattered stride-256B
// global reads per block).
// ---------------------------------------------------------------------------
__global__ __launch_bounds__(512) void k_prep(const int* __restrict__ ei, int* __restrict__ gcnt,
                                              unsigned short* __restrict__ gtok,
                                              const float* __restrict__ w1, const float* __restrict__ w2,
                                              const float* __restrict__ w3, _Float16* __restrict__ wf,
                                              const float* __restrict__ x, float* __restrict__ xW) {
    __shared__ __align__(16) unsigned char smem[64 * 1024];
    int t = threadIdx.x;

    if (blockIdx.x >= EB + 4) {   // ---- xw part ----
        _Float16* wt  = (_Float16*)smem;           // [0,32K): W1 hi/lo frags
        float*    w1s = (float*)(smem + 32768);    // [32K,64K): raw W1 rows 0-127
        for (int i = t; i < 2048; i += 512) ((float4*)w1s)[i] = ((const float4*)w1)[i];
        __syncthreads();
#pragma unroll
        for (int it = 0; it < 4; ++it) {
            int tid = it * 512 + t;          // 0..2047
            int c = tid >> 6, lane2 = tid & 63;
            int q2 = lane2 >> 4, m2 = lane2 & 15;
            int kstep = c & 3, ct = (c >> 2) & 3, term = c >> 4;
            f16x8 v;
#pragma unroll
            for (int j = 0; j < 8; ++j) {
                float wv = w1s[(kstep * 32 + q2 * 8 + j) * 64 + ct * 16 + m2];
                _Float16 hi = (_Float16)wv;
                float lo = wv - (float)hi;
                v[j] = term ? (_Float16)lo : hi;
            }
            *((f16x8*)(wt + c * 512) + lane2) = v;
        }
        __syncthreads();
        int lane = t & 63, w = t >> 6;
        int m = lane & 15, q = lane >> 4;
        for (int rb = blockIdx.x - (EB + 4); rb < XWCH; rb += XWB) {
            int rbase = rb * 128 + w * 16;
            int rowc = min(rbase + m, NN - 1);
            f16x8 Ah[4], Al[4];
#pragma unroll
            for (int ks = 0; ks < 4; ++ks) {
                const float* ar = x + (size_t)rowc * 128 + ks * 32 + q * 8;
                f32x4 f0 = *(const f32x4*)ar;
                f32x4 f1 = *(const f32x4*)(ar + 4);
                cvt_hilo(f0, f1, Ah[ks], Al[ks]);
            }
#pragma unroll
            for (int ct = 0; ct < 4; ++ct) {
                f32x4 acc = {0.f, 0.f, 0.f, 0.f};
#pragma unroll
                for (int ks = 0; ks < 4; ++ks) {
                    f16x8 Bh = *((const f16x8*)(wt + ((0 * 4 + ct) * 4 + ks) * 512) + lane);
                    f16x8 Bl = *((const f16x8*)(wt + ((1 * 4 + ct) * 4 + ks) * 512) + lane);
                    acc = __builtin_amdgcn_mfma_f32_16x16x32_f16(Ah[ks], Bh, acc, 0, 0, 0);
                    acc = __builtin_amdgcn_mfma_f32_16x16x32_f16(Al[ks], Bh, acc, 0, 0, 0);
                    acc = __builtin_amdgcn_mfma_f32_16x16x32_f16(Ah[ks], Bl, acc, 0, 0, 0);
                }
#pragma unroll
                for (int i = 0; i < 4; ++i) {
                    int r = rbase + q * 4 + i;
                    if (r < NN) xW[(size_t)r * 64 + ct * 16 + m] = acc[i];
                }
            }
        }
        return;
    }

    if (blockIdx.x >= EB) {   // ---- wprep part: W2/W3 only ----
        int tid = (blockIdx.x - EB) * 512 + t;   // 0..2047
        int c = 32 + (tid >> 6), lane = tid & 63;
        int q = lane >> 4, m = lane & 15;
        int c2 = c - 32;
        int kstep = c2 & 1, ct = (c2 >> 1) & 3, term = (c2 >> 3) & 1;
        const float* src = (c2 >> 4) ? w3 : w2;
        f16x8 v;
#pragma unroll
        for (int j = 0; j < 8; ++j) {
            float wv = src[(kstep * 32 + q * 8 + j) * 64 + ct * 16 + m];
            _Float16 hi = (_Float16)wv;
            float lo = wv - (float)hi;
            v[j] = term ? (_Float16)lo : hi;
        }
        *((f16x8*)(wf + c * 512) + lane) = v;
        return;
    }

    // ---- binning part ----
    unsigned short* stag = (unsigned short*)smem;          // 16 KB
    int* h   = (int*)(smem + 16384);                       // +2 KB
    int* esc = h + 512;
    int* cur = esc + 512;
    int* gb  = cur + 512;
    int base = blockIdx.x * C1;
    int nE = min(C1, EE - base);
    h[t] = 0; cur[t] = 0;
    __syncthreads();
    for (int i = t; i < nE; i += 512) atomicAdd(&h[ei[base + i] / NPGc], 1);
    __syncthreads();
    esc[t] = h[t];
    __syncthreads();
    for (int off = 1; off < 512; off <<= 1) {
        int u = (t >= off) ? esc[t - off] : 0;
        __syncthreads();
        esc[t] += u;
        __syncthreads();
    }
    esc[t] -= h[t];
    if (t < GG && h[t] > 0) gb[t] = atomicAdd(&gcnt[t], h[t]);
    __syncthreads();
    for (int i = t; i < nE; i += 512) {
        int s = ei[base + i], d = ei[EE + base + i];
        int g = s / NPGc;
        int ls = s - g * NPGc, ld = d - g * NPGc;
        int pos = esc[g] + atomicAdd(&cur[g], 1);
        stag[pos] = (unsigned short)(ls | (ld << 8));
    }
    __syncthreads();
    // parallel write-out: entry j's owner graph = max{g: esc[g] <= j}
    for (int j = t; j < nE; j += 512) {
        int g = 0;
#pragma unroll
        for (int step = 256; step > 0; step >>= 1) {
            int cand = g + step;
            if (cand < 512 && esc[cand] <= j) g = cand;
        }
        int off = gb[g] + (j - esc[g]);
        if (off < BSTRIDE) gtok[(size_t)g * BSTRIDE + off] = stag[j];
    }
}

// ---------------------------------------------------------------------------
// adjacency bytes (8) -> exact f16x8 A-fragment
// ---------------------------------------------------------------------------
__device__ __forceinline__ f16x8 cvt_a8(uint2 v) {
    f16x8 r;
#pragma unroll
    for (int k = 0; k < 4; ++k) r[k] = (_Float16)(float)((v.x >> (8 * k)) & 255u);
#pragma unroll
    for (int k = 0; k < 4; ++k) r[4 + k] = (_Float16)(float)((v.y >> (8 * k)) & 255u);
    return r;
}

// ---------------------------------------------------------------------------
// dense conv via MFMA: D = A(adj frags, exact f16) x T(pre-split hi/lo B-frags)
// (wave owns mts {w, w+8}, all 4 cts — fits the 128-VGPR clamp)
// ---------------------------------------------------------------------------
template <bool POOL>
__device__ __forceinline__ void conv_mfma(const _Float16* __restrict__ Tfh,
                                          const _Float16* __restrict__ Tfl,
                                          float* __restrict__ H,
                                          const f16x8 (&Af)[2][7], int w, int m, int q, int nmt,
                                          const float (&dvv)[2][4], const float (&bias)[4],
                                          float (&poolv)[4]) {
    f32x4 acc[2][4];
#pragma unroll
    for (int mi = 0; mi < 2; ++mi)
#pragma unroll
        for (int ct = 0; ct < 4; ++ct) acc[mi][ct] = (f32x4){0.f, 0.f, 0.f, 0.f};
    int lane = m + 16 * q;
#pragma unroll
    for (int ks = 0; ks < 7; ++ks) {
#pragma unroll
        for (int ct = 0; ct < 4; ++ct) {
            f16x8 Bh = *((const f16x8*)(Tfh + (ks * 4 + ct) * 512) + lane);
            f16x8 Bl = *((const f16x8*)(Tfl + (ks * 4 + ct) * 512) + lane);
            acc[0][ct] = __builtin_amdgcn_mfma_f32_16x16x32_f16(Af[0][ks], Bh, acc[0][ct], 0, 0, 0);
            acc[0][ct] = __builtin_amdgcn_mfma_f32_16x16x32_f16(Af[0][ks], Bl, acc[0][ct], 0, 0, 0);
            if (nmt > 1) {
                acc[1][ct] = __builtin_amdgcn_mfma_f32_16x16x32_f16(Af[1][ks], Bh, acc[1][ct], 0, 0, 0);
                acc[1][ct] = __builtin_amdgcn_mfma_f32_16x16x32_f16(Af[1][ks], Bl, acc[1][ct], 0, 0, 0);
            }
        }
    }
#pragma unroll
    for (int mi = 0; mi < 2; ++mi) {
        if (mi >= nmt) break;
        int rbase = (w + 8 * mi) * 16 + q * 4;
#pragma unroll
        for (int ct = 0; ct < 4; ++ct) {
            if (!POOL) {
#pragma unroll
                for (int i = 0; i < 4; ++i)
                    H[(rbase + i) * HST + ct * 16 + m] =
                        fmaxf(fmaf(dvv[mi][i], acc[mi][ct][i], bias[ct]), 0.f);
            } else {
                float pl = 0.f;
#pragma unroll
                for (int i = 0; i < 4; ++i) {
                    float o = fmaxf(fmaf(dvv[mi][i], acc[mi][ct][i], bias[ct]), 0.f);
                    if (rbase + i < NPGc) pl += o;
                }
                poolv[ct] += pl;
            }
        }
    }
}

// ---------------------------------------------------------------------------
// dense GEMM split into compute/store. gemm wave w reads EXACTLY the H rows
// conv wave w wrote (mt = w, w+8 both sides) -> same-wave LDS dependency,
// DS ops are in-order per wave -> NO barrier between conv and gemm_compute.
// The only cross-wave hazard is the T-write (WAR vs laggard conv T-reads),
// so acc is held in registers and written after a barrier.
// ---------------------------------------------------------------------------
__device__ __forceinline__ void gemm_compute(const float* __restrict__ H,
                                             const _Float16* __restrict__ wf, int w, int lane,
                                             int m, int q, int nmt, f32x4 (&gacc)[4][2]) {
    f16x8 Ah[2][2], Al[2][2];
#pragma unroll
    for (int mi = 0; mi < 2; ++mi) {
        if (mi >= nmt) break;
        int mt = w + 8 * mi;
#pragma unroll
        for (int ks = 0; ks < 2; ++ks) {
            const float* ap = H + (mt * 16 + m) * HST + ks * 32 + 8 * q;
            f32x4 a = *(const f32x4*)ap;
            f32x4 b = *(const f32x4*)(ap + 4);
            cvt_hilo(a, b, Ah[mi][ks], Al[mi][ks]);
        }
    }
#pragma unroll
    for (int ct = 0; ct < 4; ++ct) {
        f16x8 Bh0 = *((const f16x8*)(wf + ((0 * 4 + ct) * 2 + 0) * 512) + lane);
        f16x8 Bh1 = *((const f16x8*)(wf + ((0 * 4 + ct) * 2 + 1) * 512) + lane);
        f16x8 Bl0 = *((const f16x8*)(wf + ((1 * 4 + ct) * 2 + 0) * 512) + lane);
        f16x8 Bl1 = *((const f16x8*)(wf + ((1 * 4 + ct) * 2 + 1) * 512) + lane);
#pragma unroll
        for (int mi = 0; mi < 2; ++mi) {
            f32x4 acc = {0.f, 0.f, 0.f, 0.f};
            if (mi < nmt) {
                acc = __builtin_amdgcn_mfma_f32_16x16x32_f16(Ah[mi][0], Bh0, acc, 0, 0, 0);
                acc = __builtin_amdgcn_mfma_f32_16x16x32_f16(Al[mi][0], Bh0, acc, 0, 0, 0);
                acc = __builtin_amdgcn_mfma_f32_16x16x32_f16(Ah[mi][0], Bl0, acc, 0, 0, 0);
                acc = __builtin_amdgcn_mfma_f32_16x16x32_f16(Ah[mi][1], Bh1, acc, 0, 0, 0);
                acc = __builtin_amdgcn_mfma_f32_16x16x32_f16(Al[mi][1], Bh1, acc, 0, 0, 0);
                acc = __builtin_amdgcn_mfma_f32_16x16x32_f16(Ah[mi][1], Bl1, acc, 0, 0, 0);
            }
            gacc[ct][mi] = acc;
        }
    }
}

__device__ __forceinline__ void gemm_store(_Float16* __restrict__ Tfh, _Float16* __restrict__ Tfl,
                                           int w, int m, int q, int nmt,
                                           const float (&dvv)[2][4], const f32x4 (&gacc)[4][2]) {
#pragma unroll
    for (int ct = 0; ct < 4; ++ct) {
#pragma unroll
        for (int mi = 0; mi < 2; ++mi) {
            if (mi >= nmt) break;
            int mt = w + 8 * mi;
            float o[4];
#pragma unroll
            for (int i = 0; i < 4; ++i) o[i] = gacc[ct][mi][i] * dvv[mi][i];
            f16x4 hv, lv;
            cvt_hilo4(o, hv, lv);
            int quad = ((mt & 1) << 1) + (q >> 1);
            int j0 = (q & 1) << 2;
            int lanep = m + (quad << 4);
            int off = ((mt >> 1) * 4 + ct) * 512 + lanep * 8 + j0;
            *(f16x4*)(Tfh + off) = hv;
            *(f16x4*)(Tfl + off) = lv;
        }
    }
}

// ---------------------------------------------------------------------------
// Fused kernel: one block (512 thr, 8 waves) per graph. Per stage-pair:
// conv + gemm_compute run with NO internal barrier (same-wave H dep);
// barriers only bracket the T-writeout. ~156 KB LDS -> 1 block/CU,
// 2 waves/SIMD. VGPR 124, no spill (r5-measured).
// ---------------------------------------------------------------------------
__global__ __launch_bounds__(512, 2) void k_fused(
    const float* __restrict__ xW, const float* __restrict__ perm,
    const float* __restrict__ w1tail,
    const float* __restrict__ b1, const float* __restrict__ b2, const float* __restrict__ b3,
    const _Float16* __restrict__ wsW23,
    const int* __restrict__ gcnt, const unsigned short* __restrict__ gtok,
    const float* __restrict__ a1w, const float* __restrict__ a1b,
    const float* __restrict__ a2w, const float* __restrict__ a2b,
    float* __restrict__ out) {
    __shared__ __align__(16) float Hm[15808];            // union: A8 build (46592B) / H f32 (stride 76)
    __shared__ __align__(16) _Float16 Tfh[28 * 512];     // T hi frags  (28 KB)
    __shared__ __align__(16) _Float16 Tfl[28 * 512];     // T lo frags  (28 KB)
    __shared__ __align__(16) _Float16 wlds[16384];       // W2 frags [0..8K), W3 [8K..16K)
    __shared__ float w1r[640];
    __shared__ float dv[224];
    __shared__ float pool[8 * 64];
    __shared__ unsigned char idsl[672];

    unsigned char* A8  = (unsigned char*)Hm;
    unsigned int*  A32 = (unsigned int*)Hm;

    int g = blockIdx.x, t = threadIdx.x;
    int lane = t & 63, w = t >> 6;
    int m = lane & 15, q = lane >> 4;
    int nbase = g * NPGc;
    int cnt = min(gcnt[g], BSTRIDE);
    const unsigned short* tok = gtok + (size_t)g * BSTRIDE;

    // stage W2/W3 frags + w1 tail rows; zero adjacency; zero dv pad rows
    for (int i = t; i < 2048; i += 512) ((f16x8*)wlds)[i] = ((const f16x8*)wsW23)[i];
    for (int i = t; i < 640; i += 512) w1r[i] = w1tail[i];
    for (int i = t; i < 2912; i += 512) ((uint4*)A8)[i] = make_uint4(0, 0, 0, 0);
    if (t < 16) dv[208 + t] = 0.f;
    __syncthreads();
    // build adjacency (u8 packed atomics) + self-loops
    for (int i = t; i < cnt; i += 512) {
        int tk = tok[i];
        int addr = (tk >> 8) * 224 + (tk & 255);
        atomicAdd(&A32[addr >> 2], 1u << ((addr & 3) * 8));
    }
    if (t < NPGc) { int a = t * 225; atomicAdd(&A32[a >> 2], 1u << ((a & 3) * 8)); }
    // one-hot ids for the 3 perms
    for (int i = t; i < 672; i += 512) {
        int p = i / 224, nd = i - p * 224;
        int id = 0;
        if (nd < NPGc) {
            const float* pp = perm + ((size_t)p * NN + nbase + nd) * 10;
            float best = pp[0];
#pragma unroll
            for (int k = 1; k < 10; ++k) { float v = pp[k]; if (v > best) { best = v; id = k; } }
        }
        idsl[i] = (unsigned char)id;
    }
    __syncthreads();
    // adjacency A-fragments into VGPRs; deg = in-register byte row-sum + shfl
    int nmt = (w < 5) ? 2 : 1;
    f16x8 Af[2][7];
#pragma unroll
    for (int mi = 0; mi < 2; ++mi) {
        int mt = w + 8 * mi;
        if (mt < 13) {
            unsigned su = 0;
#pragma unroll
            for (int ks = 0; ks < 7; ++ks) {
                uint2 v = *(const uint2*)(A8 + (mt * 16 + m) * 224 + ks * 32 + q * 8);
                su += (v.x & 255u) + ((v.x >> 8) & 255u) + ((v.x >> 16) & 255u) + (v.x >> 24);
                su += (v.y & 255u) + ((v.y >> 8) & 255u) + ((v.y >> 16) & 255u) + (v.y >> 24);
                Af[mi][ks] = cvt_a8(v);
            }
            float rs = (float)su;
            rs += __shfl_xor(rs, 16);
            rs += __shfl_xor(rs, 32);
            if (q == 0) dv[mt * 16 + m] = (rs > 0.f) ? rsqrtf(rs) : 0.f;
        }
    }
    __syncthreads();   // A8 region now dead -> H takes over; dv ready

    float dvv[2][4];
#pragma unroll
    for (int mi = 0; mi < 2; ++mi) {
        int mt = w + 8 * mi;
#pragma unroll
        for (int i = 0; i < 4; ++i)
            dvv[mi][i] = (mt < 13) ? dv[mt * 16 + q * 4 + i] : 0.f;
    }
    float bb1[4], bb2[4], bb3[4];
#pragma unroll
    for (int ct = 0; ct < 4; ++ct) {
        bb1[ct] = b1[ct * 16 + m]; bb2[ct] = b2[ct * 16 + m]; bb3[ct] = b3[ct * 16 + m];
    }

    float poolv[4] = {0.f, 0.f, 0.f, 0.f};
    f32x4 gacc[4][2];

    for (int p = 0; p < NPERMc; ++p) {
        // conv1 input -> T frags: val = dv*(xW + w1row[id]); 8-node chunks
        // {w, w+8, w+16, w+24}; single b128 store (uniform bank footprint)
        const unsigned char* ids = idsl + p * 224;
#pragma unroll
        for (int k = 0; k < 4; ++k) {
            int c8 = w + 8 * k;
            if (c8 < 28) {
                int nd0 = c8 * 8;
                float vals[8];
#pragma unroll
                for (int i = 0; i < 8; ++i) {
                    int nd = nd0 + i;
                    float xv = (nd < NPGc) ? xW[(size_t)(nbase + nd) * 64 + lane] : 0.f;
                    vals[i] = dv[nd] * (xv + w1r[ids[nd] * 64 + lane]);  // dv=0 kills pad rows
                }
                f16x8 hv, lv;
                cvt_hilo8(vals, hv, lv);
                int off = ((c8 >> 2) * 4 + q) * 512 + (m + ((c8 & 3) << 4)) * 8;
                *(f16x8*)(Tfh + off) = hv;
                *(f16x8*)(Tfl + off) = lv;
            }
        }
        __syncthreads();
        // pair 1: conv(h1->H) + gemm(h1@W2) fused, no internal barrier
        conv_mfma<false>(Tfh, Tfl, Hm, Af, w, m, q, nmt, dvv, bb1, poolv);
        asm volatile("" ::: "memory");   // keep H writes before H reads in emission order
        gemm_compute(Hm, wlds, w, lane, m, q, nmt, gacc);
        __syncthreads();                 // all conv T-reads done
        gemm_store(Tfh, Tfl, w, m, q, nmt, dvv, gacc);
        __syncthreads();                 // T ready
        // pair 2: conv(h2->H) + gemm(h2@W3)
        conv_mfma<false>(Tfh, Tfl, Hm, Af, w, m, q, nmt, dvv, bb2, poolv);
        asm volatile("" ::: "memory");
        gemm_compute(Hm, wlds + 8192, w, lane, m, q, nmt, gacc);
        __syncthreads();
        gemm_store(Tfh, Tfl, w, m, q, nmt, dvv, gacc);
        __syncthreads();
        // conv3 -> pool
        conv_mfma<true>(Tfh, Tfl, Hm, Af, w, m, q, nmt, dvv, bb3, poolv);
        __syncthreads();                 // conv3 T-reads done before next Tbuild
    }

    // reduce pool: over q-groups (shfl) then over waves (LDS), then head MLP
#pragma unroll
    for (int ct = 0; ct < 4; ++ct) {
        float v = poolv[ct];
        v += __shfl_xor(v, 16);
        v += __shfl_xor(v, 32);
        if (q == 0) pool[w * 64 + ct * 16 + m] = v;
    }
    __syncthreads();
    if (t < 64) {
        float tot = 0.f;
#pragma unroll
        for (int i = 0; i < 8; ++i) tot += pool[i * 64 + t];
        pool[t] = tot * (1.0f / (NPGc * NPERMc));   // gsum
    }
    __syncthreads();
    if (t < 16) {
        float a = a1b[t];
        for (int k = 0; k < 64; ++k) a = fmaf(pool[k], a1w[k * 16 + t], a);
        pool[64 + t] = fmaxf(a, 0.f);
    }
    __syncthreads();
    if (t == 0) {
        float o = a2b[0];
#pragma unroll
        for (int i = 0; i < 16; ++i) o = fmaf(pool[64 + i], a2w[i], o);
        out[g] = o;
    }
}

// ---------------------------------------------------------------------------

static inline size_t alignup(size_t x) { return (x + 255) & ~(size_t)255; }

extern "C" void kernel_launch(void* const* d_in, const int* in_sizes, int n_in,
                              void* d_out, int out_size, void* d_ws, size_t ws_size,
                              hipStream_t stream) {
    const float* x    = (const float*)d_in[0];
    const int*   ei   = (const int*)d_in[1];
    // d_in[2] = batch_ids (unused: graphs are exactly 200 nodes each)
    const float* perm = (const float*)d_in[3];
    const float* w1   = (const float*)d_in[4];
    const float* b1   = (const float*)d_in[5];
    const float* w2   = (const float*)d_in[6];
    const float* b2   = (const float*)d_in[7];
    const float* w3   = (const float*)d_in[8];
    const float* b3   = (const float*)d_in[9];
    const float* a1w  = (const float*)d_in[10];
    const float* a1b  = (const float*)d_in[11];
    const float* a2w  = (const float*)d_in[12];
    const float* a2b  = (const float*)d_in[13];
    float* out = (float*)d_out;

    char* p = (char*)d_ws;
    auto take = [&](size_t bytes) { char* r = p; p += alignup(bytes); return r; };
    float*          xW   = (float*)take((size_t)NN * 64 * 4);
    unsigned short* gtok = (unsigned short*)take((size_t)GG * BSTRIDE * 2);
    _Float16*       wsW  = (_Float16*)take((size_t)64 * 512 * 2);
    int*            gcnt = (int*)take(512 * 4);
    (void)hipMemsetAsync(gcnt, 0, 512 * 4, stream);

    k_prep<<<EB + 4 + XWB, 512, 0, stream>>>(ei, gcnt, gtok, w1, w2, w3, wsW, x, xW);
    k_fused<<<GG, 512, 0, stream>>>(xW, perm, w1 + 128 * 64, b1, b2, b3,
                                    wsW + 32 * 512, gcnt, gtok,
                                    a1w, a1b, a2w, a2b, out);
}

// Round 11
// 227.622 us; speedup vs baseline: 1.2918x; 1.0153x over previous
//
#include <hip/hip_runtime.h>

// Problem constants (from reference)
#define NN   100000
#define EE   1600000
#define GG   500
#define NPGc 200
#define HH   64
#define NPERMc 3
#define C1   8192     // binning chunk (edges per block)
#define EB   196      // ceil(EE / C1)
#define XWB  256      // xw blocks (grid-stride over row chunks)
#define XWCH 782      // ceil(NN / 128) row chunks
#define HST  76       // H tile stride (f32): 16B-aligned b128 reads, uniform banks
#define BSTRIDE 4096  // fixed token-bucket stride per graph

// NOTES (hard-won, 10 rounds):
// - 1024-thread blocks: VGPR force-capped at 64 -> spill. Never.
// - 512-thread blocks: VGPR hard-clamped at 128 regardless of launch_bounds
//   2nd arg. Partitions needing >128 live VGPRs are permanently dead.
// - conv is LDS-read-bound; B-frag reads are PER-WAVE regardless of nmt.
//   13 mts over 8 waves wasted wave 7's full B-read -> 7-wave {w, w+7}
//   mapping idles wave 7 entirely (conv+gemm LDS traffic x7/8).
// - conv->gemm same-wave H dependency ({w,w+7} both sides) -> no barrier
//   between conv and gemm_compute (r5-validated elision).
// - r6: partial-pool-writers require pool zero-init (here all 8 rows are
//   written: wave 7 writes its zero row).
// - r7/r10: container infra failures; this source = r9 proposal, resubmitted.

typedef __fp16   h16x2 __attribute__((ext_vector_type(2)));   // pkrtz result type
typedef _Float16 f16x4 __attribute__((ext_vector_type(4)));
typedef _Float16 f16x8 __attribute__((ext_vector_type(8)));
typedef float    f32x4 __attribute__((ext_vector_type(4)));

// ---------------------------------------------------------------------------
// f32 -> f16 hi/lo fragment conversion (validated r4/r5)
// ---------------------------------------------------------------------------
__device__ __forceinline__ void cvt_hilo(f32x4 a, f32x4 b, f16x8& hi, f16x8& lo) {
    float f[8] = {a[0], a[1], a[2], a[3], b[0], b[1], b[2], b[3]};
#pragma unroll
    for (int j = 0; j < 8; j += 2) {
        h16x2 h = __builtin_amdgcn_cvt_pkrtz(f[j], f[j + 1]);
        h16x2 l = __builtin_amdgcn_cvt_pkrtz(f[j] - (float)h[0], f[j + 1] - (float)h[1]);
        hi[j] = (_Float16)h[0]; hi[j + 1] = (_Float16)h[1];
        lo[j] = (_Float16)l[0]; lo[j + 1] = (_Float16)l[1];
    }
}

__device__ __forceinline__ void cvt_hilo4(const float (&v)[4], f16x4& hv, f16x4& lv) {
#pragma unroll
    for (int i = 0; i < 4; i += 2) {
        h16x2 h = __builtin_amdgcn_cvt_pkrtz(v[i], v[i + 1]);
        h16x2 l = __builtin_amdgcn_cvt_pkrtz(v[i] - (float)h[0], v[i + 1] - (float)h[1]);
        hv[i] = (_Float16)h[0]; hv[i + 1] = (_Float16)h[1];
        lv[i] = (_Float16)l[0]; lv[i + 1] = (_Float16)l[1];
    }
}

__device__ __forceinline__ void cvt_hilo8(const float (&f)[8], f16x8& hi, f16x8& lo) {
#pragma unroll
    for (int j = 0; j < 8; j += 2) {
        h16x2 h = __builtin_amdgcn_cvt_pkrtz(f[j], f[j + 1]);
        h16x2 l = __builtin_amdgcn_cvt_pkrtz(f[j] - (float)h[0], f[j + 1] - (float)h[1]);
        hi[j] = (_Float16)h[0]; hi[j + 1] = (_Float16)h[1];
        lo[j] = (_Float16)l[0]; lo[j + 1] = (_Float16)l[1];
    }
}

// ---------------------------------------------------------------------------
// k_prep (merged): blocks [0,EB): bin edges into per-graph u16 token buckets.
// blocks [EB,EB+4): build W2/W3 hi/lo MFMA B-fragments into wf (c=32..63).
// blocks [EB+4,EB+4+XWB): xW = x @ W1[0:128], grid-strided over 782 row
// chunks. W1 staged into LDS via coalesced float4 loads first.
// ---------------------------------------------------------------------------
__global__ __launch_bounds__(512) void k_prep(const int* __restrict__ ei, int* __restrict__ gcnt,
                                              unsigned short* __restrict__ gtok,
                                              const float* __restrict__ w1, const float* __restrict__ w2,
                                              const float* __restrict__ w3, _Float16* __restrict__ wf,
                                              const float* __restrict__ x, float* __restrict__ xW) {
    __shared__ __align__(16) unsigned char smem[64 * 1024];
    int t = threadIdx.x;

    if (blockIdx.x >= EB + 4) {   // ---- xw part ----
        _Float16* wt  = (_Float16*)smem;           // [0,32K): W1 hi/lo frags
        float*    w1s = (float*)(smem + 32768);    // [32K,64K): raw W1 rows 0-127
        for (int i = t; i < 2048; i += 512) ((float4*)w1s)[i] = ((const float4*)w1)[i];
        __syncthreads();
#pragma unroll
        for (int it = 0; it < 4; ++it) {
            int tid = it * 512 + t;          // 0..2047
            int c = tid >> 6, lane2 = tid & 63;
            int q2 = lane2 >> 4, m2 = lane2 & 15;
            int kstep = c & 3, ct = (c >> 2) & 3, term = c >> 4;
            f16x8 v;
#pragma unroll
            for (int j = 0; j < 8; ++j) {
                float wv = w1s[(kstep * 32 + q2 * 8 + j) * 64 + ct * 16 + m2];
                _Float16 hi = (_Float16)wv;
                float lo = wv - (float)hi;
                v[j] = term ? (_Float16)lo : hi;
            }
            *((f16x8*)(wt + c * 512) + lane2) = v;
        }
        __syncthreads();
        int lane = t & 63, w = t >> 6;
        int m = lane & 15, q = lane >> 4;
        for (int rb = blockIdx.x - (EB + 4); rb < XWCH; rb += XWB) {
            int rbase = rb * 128 + w * 16;
            int rowc = min(rbase + m, NN - 1);
            f16x8 Ah[4], Al[4];
#pragma unroll
            for (int ks = 0; ks < 4; ++ks) {
                const float* ar = x + (size_t)rowc * 128 + ks * 32 + q * 8;
                f32x4 f0 = *(const f32x4*)ar;
                f32x4 f1 = *(const f32x4*)(ar + 4);
                cvt_hilo(f0, f1, Ah[ks], Al[ks]);
            }
#pragma unroll
            for (int ct = 0; ct < 4; ++ct) {
                f32x4 acc = {0.f, 0.f, 0.f, 0.f};
#pragma unroll
                for (int ks = 0; ks < 4; ++ks) {
                    f16x8 Bh = *((const f16x8*)(wt + ((0 * 4 + ct) * 4 + ks) * 512) + lane);
                    f16x8 Bl = *((const f16x8*)(wt + ((1 * 4 + ct) * 4 + ks) * 512) + lane);
                    acc = __builtin_amdgcn_mfma_f32_16x16x32_f16(Ah[ks], Bh, acc, 0, 0, 0);
                    acc = __builtin_amdgcn_mfma_f32_16x16x32_f16(Al[ks], Bh, acc, 0, 0, 0);
                    acc = __builtin_amdgcn_mfma_f32_16x16x32_f16(Ah[ks], Bl, acc, 0, 0, 0);
                }
#pragma unroll
                for (int i = 0; i < 4; ++i) {
                    int r = rbase + q * 4 + i;
                    if (r < NN) xW[(size_t)r * 64 + ct * 16 + m] = acc[i];
                }
            }
        }
        return;
    }

    if (blockIdx.x >= EB) {   // ---- wprep part: W2/W3 only ----
        int tid = (blockIdx.x - EB) * 512 + t;   // 0..2047
        int c = 32 + (tid >> 6), lane = tid & 63;
        int q = lane >> 4, m = lane & 15;
        int c2 = c - 32;
        int kstep = c2 & 1, ct = (c2 >> 1) & 3, term = (c2 >> 3) & 1;
        const float* src = (c2 >> 4) ? w3 : w2;
        f16x8 v;
#pragma unroll
        for (int j = 0; j < 8; ++j) {
            float wv = src[(kstep * 32 + q * 8 + j) * 64 + ct * 16 + m];
            _Float16 hi = (_Float16)wv;
            float lo = wv - (float)hi;
            v[j] = term ? (_Float16)lo : hi;
        }
        *((f16x8*)(wf + c * 512) + lane) = v;
        return;
    }

    // ---- binning part ----
    unsigned short* stag = (unsigned short*)smem;          // 16 KB
    int* h   = (int*)(smem + 16384);                       // +2 KB
    int* esc = h + 512;
    int* cur = esc + 512;
    int* gb  = cur + 512;
    int base = blockIdx.x * C1;
    int nE = min(C1, EE - base);
    h[t] = 0; cur[t] = 0;
    __syncthreads();
    for (int i = t; i < nE; i += 512) atomicAdd(&h[ei[base + i] / NPGc], 1);
    __syncthreads();
    esc[t] = h[t];
    __syncthreads();
    for (int off = 1; off < 512; off <<= 1) {
        int u = (t >= off) ? esc[t - off] : 0;
        __syncthreads();
        esc[t] += u;
        __syncthreads();
    }
    esc[t] -= h[t];
    if (t < GG && h[t] > 0) gb[t] = atomicAdd(&gcnt[t], h[t]);
    __syncthreads();
    for (int i = t; i < nE; i += 512) {
        int s = ei[base + i], d = ei[EE + base + i];
        int g = s / NPGc;
        int ls = s - g * NPGc, ld = d - g * NPGc;
        int pos = esc[g] + atomicAdd(&cur[g], 1);
        stag[pos] = (unsigned short)(ls | (ld << 8));
    }
    __syncthreads();
    // parallel write-out: entry j's owner graph = max{g: esc[g] <= j}
    for (int j = t; j < nE; j += 512) {
        int g = 0;
#pragma unroll
        for (int step = 256; step > 0; step >>= 1) {
            int cand = g + step;
            if (cand < 512 && esc[cand] <= j) g = cand;
        }
        int off = gb[g] + (j - esc[g]);
        if (off < BSTRIDE) gtok[(size_t)g * BSTRIDE + off] = stag[j];
    }
}

// ---------------------------------------------------------------------------
// adjacency bytes (8) -> exact f16x8 A-fragment
// ---------------------------------------------------------------------------
__device__ __forceinline__ f16x8 cvt_a8(uint2 v) {
    f16x8 r;
#pragma unroll
    for (int k = 0; k < 4; ++k) r[k] = (_Float16)(float)((v.x >> (8 * k)) & 255u);
#pragma unroll
    for (int k = 0; k < 4; ++k) r[4 + k] = (_Float16)(float)((v.y >> (8 * k)) & 255u);
    return r;
}

// ---------------------------------------------------------------------------
// dense conv via MFMA: D = A(adj frags) x T(hi/lo B-frags).
// 7-wave mapping: wave w (< 7) owns mts {w, w+7}; wave 7 idle (no B reads).
// ---------------------------------------------------------------------------
template <bool POOL>
__device__ __forceinline__ void conv_mfma(const _Float16* __restrict__ Tfh,
                                          const _Float16* __restrict__ Tfl,
                                          float* __restrict__ H,
                                          const f16x8 (&Af)[2][7], int w, int m, int q, int nmt,
                                          const float (&dvv)[2][4], const float (&bias)[4],
                                          float (&poolv)[4]) {
    f32x4 acc[2][4];
#pragma unroll
    for (int mi = 0; mi < 2; ++mi)
#pragma unroll
        for (int ct = 0; ct < 4; ++ct) acc[mi][ct] = (f32x4){0.f, 0.f, 0.f, 0.f};
    int lane = m + 16 * q;
#pragma unroll
    for (int ks = 0; ks < 7; ++ks) {
#pragma unroll
        for (int ct = 0; ct < 4; ++ct) {
            f16x8 Bh = *((const f16x8*)(Tfh + (ks * 4 + ct) * 512) + lane);
            f16x8 Bl = *((const f16x8*)(Tfl + (ks * 4 + ct) * 512) + lane);
            acc[0][ct] = __builtin_amdgcn_mfma_f32_16x16x32_f16(Af[0][ks], Bh, acc[0][ct], 0, 0, 0);
            acc[0][ct] = __builtin_amdgcn_mfma_f32_16x16x32_f16(Af[0][ks], Bl, acc[0][ct], 0, 0, 0);
            if (nmt > 1) {
                acc[1][ct] = __builtin_amdgcn_mfma_f32_16x16x32_f16(Af[1][ks], Bh, acc[1][ct], 0, 0, 0);
                acc[1][ct] = __builtin_amdgcn_mfma_f32_16x16x32_f16(Af[1][ks], Bl, acc[1][ct], 0, 0, 0);
            }
        }
    }
#pragma unroll
    for (int mi = 0; mi < 2; ++mi) {
        if (mi >= nmt) break;
        int rbase = (w + 7 * mi) * 16 + q * 4;
#pragma unroll
        for (int ct = 0; ct < 4; ++ct) {
            if (!POOL) {
#pragma unroll
                for (int i = 0; i < 4; ++i)
                    H[(rbase + i) * HST + ct * 16 + m] =
                        fmaxf(fmaf(dvv[mi][i], acc[mi][ct][i], bias[ct]), 0.f);
            } else {
                float pl = 0.f;
#pragma unroll
                for (int i = 0; i < 4; ++i) {
                    float o = fmaxf(fmaf(dvv[mi][i], acc[mi][ct][i], bias[ct]), 0.f);
                    if (rbase + i < NPGc) pl += o;
                }
                poolv[ct] += pl;
            }
        }
    }
}

// ---------------------------------------------------------------------------
// dense GEMM split into compute/store. gemm wave w reads EXACTLY the H rows
// conv wave w wrote (mts {w, w+7} both sides) -> same-wave LDS dependency,
// no barrier between conv and gemm_compute. T-write after barrier.
// ---------------------------------------------------------------------------
__device__ __forceinline__ void gemm_compute(const float* __restrict__ H,
                                             const _Float16* __restrict__ wf, int w, int lane,
                                             int m, int q, int nmt, f32x4 (&gacc)[4][2]) {
    f16x8 Ah[2][2], Al[2][2];
#pragma unroll
    for (int mi = 0; mi < 2; ++mi) {
        if (mi >= nmt) break;
        int mt = w + 7 * mi;
#pragma unroll
        for (int ks = 0; ks < 2; ++ks) {
            const float* ap = H + (mt * 16 + m) * HST + ks * 32 + 8 * q;
            f32x4 a = *(const f32x4*)ap;
            f32x4 b = *(const f32x4*)(ap + 4);
            cvt_hilo(a, b, Ah[mi][ks], Al[mi][ks]);
        }
    }
#pragma unroll
    for (int ct = 0; ct < 4; ++ct) {
        f16x8 Bh0 = *((const f16x8*)(wf + ((0 * 4 + ct) * 2 + 0) * 512) + lane);
        f16x8 Bh1 = *((const f16x8*)(wf + ((0 * 4 + ct) * 2 + 1) * 512) + lane);
        f16x8 Bl0 = *((const f16x8*)(wf + ((1 * 4 + ct) * 2 + 0) * 512) + lane);
        f16x8 Bl1 = *((const f16x8*)(wf + ((1 * 4 + ct) * 2 + 1) * 512) + lane);
#pragma unroll
        for (int mi = 0; mi < 2; ++mi) {
            f32x4 acc = {0.f, 0.f, 0.f, 0.f};
            if (mi < nmt) {
                acc = __builtin_amdgcn_mfma_f32_16x16x32_f16(Ah[mi][0], Bh0, acc, 0, 0, 0);
                acc = __builtin_amdgcn_mfma_f32_16x16x32_f16(Al[mi][0], Bh0, acc, 0, 0, 0);
                acc = __builtin_amdgcn_mfma_f32_16x16x32_f16(Ah[mi][0], Bl0, acc, 0, 0, 0);
                acc = __builtin_amdgcn_mfma_f32_16x16x32_f16(Ah[mi][1], Bh1, acc, 0, 0, 0);
                acc = __builtin_amdgcn_mfma_f32_16x16x32_f16(Al[mi][1], Bh1, acc, 0, 0, 0);
                acc = __builtin_amdgcn_mfma_f32_16x16x32_f16(Ah[mi][1], Bl1, acc, 0, 0, 0);
            }
            gacc[ct][mi] = acc;
        }
    }
}

__device__ __forceinline__ void gemm_store(_Float16* __restrict__ Tfh, _Float16* __restrict__ Tfl,
                                           int w, int m, int q, int nmt,
                                           const float (&dvv)[2][4], const f32x4 (&gacc)[4][2]) {
#pragma unroll
    for (int ct = 0; ct < 4; ++ct) {
#pragma unroll
        for (int mi = 0; mi < 2; ++mi) {
            if (mi >= nmt) break;
            int mt = w + 7 * mi;
            float o[4];
#pragma unroll
            for (int i = 0; i < 4; ++i) o[i] = gacc[ct][mi][i] * dvv[mi][i];
            f16x4 hv, lv;
            cvt_hilo4(o, hv, lv);
            int quad = ((mt & 1) << 1) + (q >> 1);
            int j0 = (q & 1) << 2;
            int lanep = m + (quad << 4);
            int off = ((mt >> 1) * 4 + ct) * 512 + lanep * 8 + j0;
            *(f16x4*)(Tfh + off) = hv;
            *(f16x4*)(Tfl + off) = lv;
        }
    }
}

// ---------------------------------------------------------------------------
// Fused kernel: one block (512 thr, 8 waves) per graph. Waves 0-6 own conv/
// gemm mts {w, w+7} (wave 6: 1 mt, wave 7: idle -> saves 1/8 of conv+gemm
// LDS reads). conv + gemm_compute barrier-free (same-wave H dep); barriers
// bracket T-writeout. ~156 KB LDS -> 1 block/CU, 2 waves/SIMD.
// ---------------------------------------------------------------------------
__global__ __launch_bounds__(512, 2) void k_fused(
    const float* __restrict__ xW, const float* __restrict__ perm,
    const float* __restrict__ w1tail,
    const float* __restrict__ b1, const float* __restrict__ b2, const float* __restrict__ b3,
    const _Float16* __restrict__ wsW23,
    const int* __restrict__ gcnt, const unsigned short* __restrict__ gtok,
    const float* __restrict__ a1w, const float* __restrict__ a1b,
    const float* __restrict__ a2w, const float* __restrict__ a2b,
    float* __restrict__ out) {
    __shared__ __align__(16) float Hm[15808];            // union: A8 build (46592B) / H f32 (stride 76)
    __shared__ __align__(16) _Float16 Tfh[28 * 512];     // T hi frags  (28 KB)
    __shared__ __align__(16) _Float16 Tfl[28 * 512];     // T lo frags  (28 KB)
    __shared__ __align__(16) _Float16 wlds[16384];       // W2 frags [0..8K), W3 [8K..16K)
    __shared__ float w1r[640];
    __shared__ float dv[224];
    __shared__ float pool[8 * 64];
    __shared__ unsigned char idsl[672];

    unsigned char* A8  = (unsigned char*)Hm;
    unsigned int*  A32 = (unsigned int*)Hm;

    int g = blockIdx.x, t = threadIdx.x;
    int lane = t & 63, w = t >> 6;
    int m = lane & 15, q = lane >> 4;
    int nbase = g * NPGc;
    int cnt = min(gcnt[g], BSTRIDE);
    const unsigned short* tok = gtok + (size_t)g * BSTRIDE;

    // stage W2/W3 frags + w1 tail rows; zero adjacency; zero dv pad rows
    for (int i = t; i < 2048; i += 512) ((f16x8*)wlds)[i] = ((const f16x8*)wsW23)[i];
    for (int i = t; i < 640; i += 512) w1r[i] = w1tail[i];
    for (int i = t; i < 2912; i += 512) ((uint4*)A8)[i] = make_uint4(0, 0, 0, 0);
    if (t < 16) dv[208 + t] = 0.f;
    __syncthreads();
    // build adjacency (u8 packed atomics) + self-loops
    for (int i = t; i < cnt; i += 512) {
        int tk = tok[i];
        int addr = (tk >> 8) * 224 + (tk & 255);
        atomicAdd(&A32[addr >> 2], 1u << ((addr & 3) * 8));
    }
    if (t < NPGc) { int a = t * 225; atomicAdd(&A32[a >> 2], 1u << ((a & 3) * 8)); }
    // one-hot ids for the 3 perms (float2 loads: 8B-aligned, same compares)
    for (int i = t; i < 672; i += 512) {
        int p = i / 224, nd = i - p * 224;
        int id = 0;
        if (nd < NPGc) {
            const float* pp = perm + ((size_t)p * NN + nbase + nd) * 10;
            float2 u0 = *(const float2*)pp;
            float2 u1 = *(const float2*)(pp + 2);
            float2 u2 = *(const float2*)(pp + 4);
            float2 u3 = *(const float2*)(pp + 6);
            float2 u4 = *(const float2*)(pp + 8);
            float vv[10] = {u0.x, u0.y, u1.x, u1.y, u2.x, u2.y, u3.x, u3.y, u4.x, u4.y};
            float best = vv[0];
#pragma unroll
            for (int k = 1; k < 10; ++k) { if (vv[k] > best) { best = vv[k]; id = k; } }
        }
        idsl[i] = (unsigned char)id;
    }
    __syncthreads();
    // adjacency A-fragments into VGPRs (7-wave mapping {w, w+7});
    // deg = in-register byte row-sum + shfl -> dv (each mt written once)
    int nmt = (w < 6) ? 2 : ((w == 6) ? 1 : 0);
    f16x8 Af[2][7];
#pragma unroll
    for (int mi = 0; mi < 2; ++mi) {
        int mt = w + 7 * mi;
        if (w < 7 && mt < 13) {
            unsigned su = 0;
#pragma unroll
            for (int ks = 0; ks < 7; ++ks) {
                uint2 v = *(const uint2*)(A8 + (mt * 16 + m) * 224 + ks * 32 + q * 8);
                su += (v.x & 255u) + ((v.x >> 8) & 255u) + ((v.x >> 16) & 255u) + (v.x >> 24);
                su += (v.y & 255u) + ((v.y >> 8) & 255u) + ((v.y >> 16) & 255u) + (v.y >> 24);
                Af[mi][ks] = cvt_a8(v);
            }
            float rs = (float)su;
            rs += __shfl_xor(rs, 16);
            rs += __shfl_xor(rs, 32);
            if (q == 0) dv[mt * 16 + m] = (rs > 0.f) ? rsqrtf(rs) : 0.f;
        }
    }
    __syncthreads();   // A8 region now dead -> H takes over; dv ready

    float dvv[2][4];
#pragma unroll
    for (int mi = 0; mi < 2; ++mi) {
        int mt = w + 7 * mi;
        bool ok = (w < 7) && (mt < 13);
#pragma unroll
        for (int i = 0; i < 4; ++i)
            dvv[mi][i] = ok ? dv[mt * 16 + q * 4 + i] : 0.f;
    }
    float bb1[4], bb2[4], bb3[4];
#pragma unroll
    for (int ct = 0; ct < 4; ++ct) {
        bb1[ct] = b1[ct * 16 + m]; bb2[ct] = b2[ct * 16 + m]; bb3[ct] = b3[ct * 16 + m];
    }

    float poolv[4] = {0.f, 0.f, 0.f, 0.f};
    f32x4 gacc[4][2];

    for (int p = 0; p < NPERMc; ++p) {
        // conv1 input -> T frags: val = dv*(xW + w1row[id]); 8-node chunks
        // {w, w+8, w+16, w+24}; single b128 store (uniform bank footprint)
        const unsigned char* ids = idsl + p * 224;
#pragma unroll
        for (int k = 0; k < 4; ++k) {
            int c8 = w + 8 * k;
            if (c8 < 28) {
                int nd0 = c8 * 8;
                float vals[8];
#pragma unroll
                for (int i = 0; i < 8; ++i) {
                    int nd = nd0 + i;
                    float xv = (nd < NPGc) ? xW[(size_t)(nbase + nd) * 64 + lane] : 0.f;
                    vals[i] = dv[nd] * (xv + w1r[ids[nd] * 64 + lane]);  // dv=0 kills pad rows
                }
                f16x8 hv, lv;
                cvt_hilo8(vals, hv, lv);
                int off = ((c8 >> 2) * 4 + q) * 512 + (m + ((c8 & 3) << 4)) * 8;
                *(f16x8*)(Tfh + off) = hv;
                *(f16x8*)(Tfl + off) = lv;
            }
        }
        __syncthreads();
        // pair 1: conv(h1->H) + gemm(h1@W2) fused, no internal barrier.
        // Wave 7 (nmt==0) skips both entirely (no LDS reads). Guards contain
        // no barriers -> block-level sync structure uniform.
        if (nmt) {
            conv_mfma<false>(Tfh, Tfl, Hm, Af, w, m, q, nmt, dvv, bb1, poolv);
            asm volatile("" ::: "memory");   // keep H writes before H reads in emission order
            gemm_compute(Hm, wlds, w, lane, m, q, nmt, gacc);
        }
        __syncthreads();                 // all conv T-reads done
        if (nmt) gemm_store(Tfh, Tfl, w, m, q, nmt, dvv, gacc);
        __syncthreads();                 // T ready
        // pair 2: conv(h2->H) + gemm(h2@W3)
        if (nmt) {
            conv_mfma<false>(Tfh, Tfl, Hm, Af, w, m, q, nmt, dvv, bb2, poolv);
            asm volatile("" ::: "memory");
            gemm_compute(Hm, wlds + 8192, w, lane, m, q, nmt, gacc);
        }
        __syncthreads();
        if (nmt) gemm_store(Tfh, Tfl, w, m, q, nmt, dvv, gacc);
        __syncthreads();
        // conv3 -> pool
        if (nmt) conv_mfma<true>(Tfh, Tfl, Hm, Af, w, m, q, nmt, dvv, bb3, poolv);
        __syncthreads();                 // conv3 T-reads done before next Tbuild
    }

    // reduce pool: over q-groups (shfl) then over waves (LDS), then head MLP.
    // Wave 7's poolv is all zeros -> its pool row contributes nothing.
#pragma unroll
    for (int ct = 0; ct < 4; ++ct) {
        float v = poolv[ct];
        v += __shfl_xor(v, 16);
        v += __shfl_xor(v, 32);
        if (q == 0) pool[w * 64 + ct * 16 + m] = v;
    }
    __syncthreads();
    if (t < 64) {
        float tot = 0.f;
#pragma unroll
        for (int i = 0; i < 8; ++i) tot += pool[i * 64 + t];
        pool[t] = tot * (1.0f / (NPGc * NPERMc));   // gsum
    }
    __syncthreads();
    if (t < 16) {
        float a = a1b[t];
        for (int k = 0; k < 64; ++k) a = fmaf(pool[k], a1w[k * 16 + t], a);
        pool[64 + t] = fmaxf(a, 0.f);
    }
    __syncthreads();
    if (t == 0) {
        float o = a2b[0];
#pragma unroll
        for (int i = 0; i < 16; ++i) o = fmaf(pool[64 + i], a2w[i], o);
        out[g] = o;
    }
}

// ---------------------------------------------------------------------------

static inline size_t alignup(size_t x) { return (x + 255) & ~(size_t)255; }

extern "C" void kernel_launch(void* const* d_in, const int* in_sizes, int n_in,
                              void* d_out, int out_size, void* d_ws, size_t ws_size,
                              hipStream_t stream) {
    const float* x    = (const float*)d_in[0];
    const int*   ei   = (const int*)d_in[1];
    // d_in[2] = batch_ids (unused: graphs are exactly 200 nodes each)
    const float* perm = (const float*)d_in[3];
    const float* w1   = (const float*)d_in[4];
    const float* b1   = (const float*)d_in[5];
    const float* w2   = (const float*)d_in[6];
    const float* b2   = (const float*)d_in[7];
    const float* w3   = (const float*)d_in[8];
    const float* b3   = (const float*)d_in[9];
    const float* a1w  = (const float*)d_in[10];
    const float* a1b  = (const float*)d_in[11];
    const float* a2w  = (const float*)d_in[12];
    const float* a2b  = (const float*)d_in[13];
    float* out = (float*)d_out;

    char* p = (char*)d_ws;
    auto take = [&](size_t bytes) { char* r = p; p += alignup(bytes); return r; };
    float*          xW   = (float*)take((size_t)NN * 64 * 4);
    unsigned short* gtok = (unsigned short*)take((size_t)GG * BSTRIDE * 2);
    _Float16*       wsW  = (_Float16*)take((size_t)64 * 512 * 2);
    int*            gcnt = (int*)take(512 * 4);
    (void)hipMemsetAsync(gcnt, 0, 512 * 4, stream);

    k_prep<<<EB + 4 + XWB, 512, 0, stream>>>(ei, gcnt, gtok, w1, w2, w3, wsW, x, xW);
    k_fused<<<GG, 512, 0, stream>>>(xW, perm, w1 + 128 * 64, b1, b2, b3,
                                    wsW + 32 * 512, gcnt, gtok,
                                    a1w, a1b, a2w, a2b, out);
}